// Round 10
// baseline (19388.918 us; speedup 1.0000x reference)
//
#include <hip/hip_runtime.h>
#include <hip/hip_bf16.h>

#define AGENT __HIP_MEMORY_SCOPE_AGENT
#define RLX __ATOMIC_RELAXED
typedef unsigned long long u64t;

typedef _Float16 h2 __attribute__((ext_vector_type(2)));
union U32H2 { unsigned u; h2 h; };
__device__ __forceinline__ h2 uh(unsigned u){ U32H2 c; c.u=u; return c.h; }
__device__ __forceinline__ unsigned pk(float a, float b){
  U32H2 c; c.h = h2{(_Float16)a, (_Float16)b}; return c.u;
}
#define RCPF(x) __builtin_amdgcn_rcpf(x)

__device__ __forceinline__ float DOT2(unsigned a, unsigned b, float acc){
#if __has_builtin(__builtin_amdgcn_fdot2)
  return __builtin_amdgcn_fdot2(uh(a), uh(b), acc, false);
#else
  h2 x = uh(a), y = uh(b);
  acc = fmaf((float)x[0], (float)y[0], acc);
  return fmaf((float)x[1], (float)y[1], acc);
#endif
}
__device__ __forceinline__ float sigm(float x){ return RCPF(1.0f+__expf(-x)); }
__device__ __forceinline__ float ftanh(float x){ return 1.0f - 2.0f*RCPF(1.0f+__expf(x+x)); }

// ---------- value-tagged pub/poll (relaxed 64-bit agent atomics; R7-R9 proven) ----------
__device__ __forceinline__ void pubw(u64t* p, unsigned seq, unsigned data){
  __hip_atomic_store(p, ((u64t)seq<<32)|(u64t)data, RLX, AGENT);
}
template<int K>
__device__ __forceinline__ void waitN(const u64t* base, const int* off, unsigned seq,
                                      unsigned* out, unsigned* kf){
  long n=0;
  for(;;){
    u64t v[K]; bool ok=true;
    #pragma unroll
    for(int k=0;k<K;k++) v[k]=__hip_atomic_load(base+off[k], RLX, AGENT);
    #pragma unroll
    for(int k=0;k<K;k++) ok &= ((unsigned)(v[k]>>32)==seq);
    if(ok){
      #pragma unroll
      for(int k=0;k<K;k++) out[k]=(unsigned)v[k];
      return;
    }
    __builtin_amdgcn_s_sleep(1);
    if((++n&63)==0){
      if(__hip_atomic_load(kf,RLX,AGENT)!=0u) break;
      if(n>300000L){ __hip_atomic_store(kf,1u,RLX,AGENT); break; }
    }
  }
  #pragma unroll
  for(int k=0;k<K;k++) out[k]=0u;
}

// ---------------- one-time weight folds (f32 GEMM inputs) ----------------
__global__ void k_fold(const float* __restrict__ Wp, const float* __restrict__ Wq,
                       const float* __restrict__ Wg,
                       float* __restrict__ WpT, float* __restrict__ WqT,
                       float* __restrict__ WgupT, float* __restrict__ WgcT)
{
  int i0 = blockIdx.x*blockDim.x+threadIdx.x;
  int st = gridDim.x*blockDim.x;
  for(int o=i0;o<512*150;o+=st){ int h=o%150, i=o/150;
    WpT[o]=Wp[h*1024+i]+Wp[h*1024+512+i];
    WqT[o]=Wq[h*1024+i]+Wq[h*1024+512+i]; }
  for(int o=i0;o<512*1024;o+=st){ int i=o&511, j=o>>9;
    size_t rb=(size_t)(1024+j)*2048;
    WgupT[(size_t)i*1024+j]=Wg[rb+i]+Wg[rb+512+i];
    WgcT [(size_t)i*1024+j]=Wg[rb+1024+i]+Wg[rb+1536+i]; }
}

// pair layouts: WihT[jp*456+k] (coalesced in k), WhhP[p*456+k], WvU[p*152+h]
__global__ void k_fold2(const float* __restrict__ Wih,
                        const float* __restrict__ Whh, const float* __restrict__ Wv,
                        unsigned* __restrict__ WihT,
                        unsigned* __restrict__ WhhP, unsigned* __restrict__ WvU)
{
  int i0 = blockIdx.x*blockDim.x+threadIdx.x;
  int st = gridDim.x*blockDim.x;
  for(int o=i0;o<512*456;o+=st){ int k=o%456, jp=o/456;
    unsigned v = 0u;
    if(k<450) v = pk(Wih[(size_t)k*1024+2*jp], Wih[(size_t)k*1024+2*jp+1]);
    WihT[o] = v; }
  for(int o=i0;o<76*456;o+=st){ int k=o%456, p=o/456;
    float x=0.f,y=0.f;
    if(k<450){ if(2*p<150) x=Whh[k*150+2*p]; if(2*p+1<150) y=Whh[k*150+2*p+1]; }
    WhhP[o]=pk(x,y); }
  for(int o=i0;o<76*152;o+=st){ int h=o%152, p=o/152;
    float x=0.f,y=0.f;
    if(h<150){ if(2*p<150) x=Wv[h*150+2*p]; if(2*p+1<150) y=Wv[h*150+2*p+1]; }
    WvU[o]=pk(x,y); }
}

// uq (q,b,i) f32 -> uqP[(b*512+i)*128 + qp] pairs over q
__global__ __launch_bounds__(256) void k_uqp(const float* __restrict__ uq, unsigned* __restrict__ uqP){
  __shared__ float Al[32*512];
  int b = blockIdx.x, qt = blockIdx.y, tid = threadIdx.x;
  for(int o4=tid;o4<4096;o4+=256){ int m=o4>>7, i4=o4&127;
    ((float4*)Al)[o4] = *(const float4*)&uq[(size_t)(qt*32+m)*16384 + b*512 + i4*4]; }
  __syncthreads();
  for(int o=tid;o<8192;o+=256){ int i=o>>4, p=o&15;
    uqP[((size_t)b*512+i)*128 + qt*16 + p] = pk(Al[(2*p)*512+i], Al[(2*p+1)*512+i]); }
}

// precompute GEMMs: MODE0 Wuph[b][t][152] ; MODE3 WqUqh[b][q][152] ; MODE4 Gup3[b][t][1024]
template<int MODE>
__global__ __launch_bounds__(256) void k_gemm(const float* __restrict__ A,
   const float* __restrict__ WT, _Float16* __restrict__ oH, int N)
{
  __shared__ float Al[32*512];
  int mt=blockIdx.x, nt=blockIdx.y, tid=threadIdx.x;
  const float* Ab = A + (size_t)mt*16384;
  for(int o=tid;o<4096;o+=256) ((float4*)Al)[o]=((const float4*)Ab)[o];
  __syncthreads();
  int n = nt*256+tid;
  if(n>=N) return;
  float acc[32];
  #pragma unroll
  for(int m=0;m<32;m++) acc[m]=0.f;
  const float* wp = WT + n;
  #pragma unroll 2
  for(int k=0;k<512;k+=2){
    float w0 = wp[(size_t)k*N], w1 = wp[(size_t)(k+1)*N];
    #pragma unroll
    for(int m=0;m<32;m++) acc[m]=fmaf(w0, Al[m*512+k], acc[m]);
    #pragma unroll
    for(int m=0;m<32;m++) acc[m]=fmaf(w1, Al[m*512+k+1], acc[m]);
  }
  if(MODE==0){
    #pragma unroll
    for(int m=0;m<32;m++) oH[((size_t)m*512 + mt)*152 + n] = (_Float16)acc[m];
  } else if(MODE==3){
    #pragma unroll
    for(int m=0;m<32;m++) oH[((size_t)m*256 + mt)*152 + n] = (_Float16)acc[m];
  } else {
    #pragma unroll
    for(int m=0;m<32;m++) oH[((size_t)m*512 + mt)*1024 + n] = (_Float16)acc[m];
  }
}

// M[b] = uq[b] @ WgcT : Mp[(b*1024+j)*128 + qp]
__global__ __launch_bounds__(256) void k_gemmM(const float* __restrict__ uq,
   const float* __restrict__ WgcT, unsigned* __restrict__ Mp)
{
  __shared__ float Al[32*512];
  int b=blockIdx.x, qt=blockIdx.y, nt=blockIdx.z, tid=threadIdx.x;
  for(int o4=tid;o4<4096;o4+=256){ int m=o4>>7, i4=o4&127;
    ((float4*)Al)[o4] = *(const float4*)&uq[(size_t)(qt*32+m)*16384 + b*512 + i4*4]; }
  __syncthreads();
  int n = nt*256+tid;
  float acc[32];
  #pragma unroll
  for(int m=0;m<32;m++) acc[m]=0.f;
  const float* wp = WgcT + n;
  #pragma unroll 2
  for(int k=0;k<512;k+=2){
    float w0 = wp[(size_t)k*1024], w1 = wp[(size_t)(k+1)*1024];
    #pragma unroll
    for(int m=0;m<32;m++) acc[m]=fmaf(w0, Al[m*512+k], acc[m]);
    #pragma unroll
    for(int m=0;m<32;m++) acc[m]=fmaf(w1, Al[m*512+k+1], acc[m]);
  }
  #pragma unroll
  for(int p=0;p<16;p++)
    Mp[((size_t)b*1024 + n)*128 + qt*16 + p] = pk(acc[2*p], acc[2*p+1]);
}

__global__ void k_init(unsigned* comm){
  int i = blockIdx.x*blockDim.x + threadIdx.x;
  if(i < 57860) comm[i] = 0u;
}

// ---------------- persistent: 128 symmetric blocks, ONE hop per step ----------------
struct __align__(16) SMW {
  unsigned M[128*257];                 // 131.6KB [qp][jl] stride 257
  unsigned a2[128], gupl[128], cpr[128], wupl[80], vp[80];
  float v[152], V[152], w2[152], s_[256], a_[256];
  float ccf[128], Gc[256], c_f[256];
  float gi[452], rgh[2][452], bi[452], bh[452];
  float rgi[2][452];
};

__global__ __launch_bounds__(1024) void persist(
  const unsigned* __restrict__ uqP,   const unsigned* __restrict__ Mp,
  const unsigned* __restrict__ Gup3u, const unsigned* __restrict__ Wuphu,
  const unsigned* __restrict__ WqUqhu, const unsigned* __restrict__ WihTu,
  const unsigned* __restrict__ WhhP,  const unsigned* __restrict__ WvUg,
  const float* __restrict__ v0, const float* __restrict__ Vin,
  const float* __restrict__ bih, const float* __restrict__ bhh,
  u64t* giP, unsigned* kf,
  float* __restrict__ dout)
{
  extern __shared__ char smraw[];
  SMW& S = *reinterpret_cast<SMW*>(smraw);
  const int tid = threadIdx.x;
  const int b = blockIdx.x>>2, s = blockIdx.x&3;

  // ---- prologue: M j-slice in LDS; v,V,biases ----
  for(int o=tid;o<32768;o+=1024){
    int qp=o&127, jl=o>>7;
    int j = s*128 + (jl&127) + ((jl>>7)<<9);
    S.M[qp*257+jl] = Mp[((size_t)b*1024+j)*128+qp];
  }
  for(int o=tid;o<152;o+=1024){
    S.v[o]=(o<150)?v0[b*150+o]:0.f;
    S.V[o]=(o<150)?Vin[b*150+o]:0.f; }
  for(int o=tid;o<452;o+=1024){
    S.bi[o]=(o<450)?bih[o]:0.f;
    S.bh[o]=(o<450)?bhh[o]:0.f; }
  __syncthreads();
  if(tid<76) S.vp[tid]=pk(S.v[2*tid],S.v[2*tid+1]);

  const int gib = b*904;               // [b][4 slots][226]
  const int myslot = gib + s*226;
  const int kk_ = tid&511, half_ = tid>>9;

  for(int t=0;t<512;++t){
    // prefetch t-indexed streams (independent of the hop)
    unsigned wupr = (tid<76)? Wuphu[((size_t)b*512+t)*76+tid] : 0u;
    unsigned gupr = 0u;
    if(tid<128){
      int wi = (tid<64)? (s*64+tid) : (256+s*64+tid-64);
      gupr = Gup3u[((size_t)b*512+t)*512 + wi];
    }
    if(t>0){
      // ---- THE hop: poll 4 gi partials (incl. own) ----
      if(tid<225){
        int off[4]={gib+tid, gib+226+tid, gib+452+tid, gib+678+tid};
        unsigned gv[4];
        waitN<4>(giP,off,(unsigned)t,gv,kf);
        float g0=0.f,g1=0.f;
        #pragma unroll
        for(int k=0;k<4;k++){ h2 x=uh(gv[k]); g0+=(float)x[0]; g1+=(float)x[1]; }
        S.gi[2*tid]=g0; S.gi[2*tid+1]=g1;
      }
      __syncthreads();
      if(tid<150){
        float gh0=S.rgh[0][tid]+S.rgh[1][tid]+S.bh[tid];
        float gh1=S.rgh[0][150+tid]+S.rgh[1][150+tid]+S.bh[150+tid];
        float gh2=S.rgh[0][300+tid]+S.rgh[1][300+tid]+S.bh[300+tid];
        float rg=sigm(S.gi[tid]+S.bi[tid] + gh0);
        float zg=sigm(S.gi[150+tid]+S.bi[150+tid] + gh1);
        float ng=ftanh(S.gi[300+tid]+S.bi[300+tid] + rg*gh2);
        float vn=fmaf(zg, S.v[tid]-ng, ng);
        S.v[tid]=vn;
        if(s==0) dout[((size_t)(t-1)*32+b)*150+tid]=vn;
      }
      __syncthreads();
      if(tid<76) S.vp[tid]=pk(S.v[2*tid],S.v[2*tid+1]);
    }
    if(tid<76)  S.wupl[tid]=wupr;
    if(tid<128) S.gupl[tid]=gupr;
    __syncthreads();

    // ---- w2 = wup + Wv.v (WvU streamed, coalesced in h) ----
    if(tid<608){
      int h=tid>>2, qd=tid&3;
      float acc=0.f;
      if(h<150){
        #pragma unroll
        for(int p=qd*19;p<qd*19+19;p++) acc=DOT2(WvUg[p*152+h], S.vp[p], acc);
      }
      acc+=__shfl_xor(acc,1,64); acc+=__shfl_xor(acc,2,64);
      if(h<150&&qd==0){ h2 ww=uh(S.wupl[h>>1]); S.w2[h]=acc+(float)ww[h&1]; }
    }
    __syncthreads();

    // ---- s[q] = sum_h V[h] tanh(w2[h]+WqUq[q,h]) (WqUq streamed) ----
    {
      int q=tid>>2, hq=tid&3;
      int hp0=hq*19, hp1=(hq==3)?75:hp0+19;
      const unsigned* wq = WqUqhu + ((size_t)b*256+q)*76;
      float acc=0.f;
      for(int hp=hp0;hp<hp1;hp++){
        h2 wp=uh(wq[hp]);
        acc=fmaf(S.V[2*hp],   ftanh(S.w2[2*hp]  +(float)wp[0]), acc);
        acc=fmaf(S.V[2*hp+1], ftanh(S.w2[2*hp+1]+(float)wp[1]), acc);
      }
      acc+=__shfl_xor(acc,1,64); acc+=__shfl_xor(acc,2,64);
      if(hq==0) S.s_[q]=acc;
    }
    __syncthreads();
    if(tid<64){
      float x0=S.s_[tid],x1=S.s_[tid+64],x2=S.s_[tid+128],x3=S.s_[tid+192];
      float mx=fmaxf(fmaxf(x0,x1),fmaxf(x2,x3));
      #pragma unroll
      for(int o=1;o<64;o<<=1) mx=fmaxf(mx,__shfl_xor(mx,o,64));
      float e0=__expf(x0-mx),e1=__expf(x1-mx),e2=__expf(x2-mx),e3=__expf(x3-mx);
      float sm=e0+e1+e2+e3;
      #pragma unroll
      for(int o=1;o<64;o<<=1) sm+=__shfl_xor(sm,o,64);
      float rs=RCPF(sm);
      S.a_[tid]=e0*rs; S.a_[tid+64]=e1*rs; S.a_[tid+128]=e2*rs; S.a_[tid+192]=e3*rs;
    }
    __syncthreads();
    if(tid<128) S.a2[tid]=pk(S.a_[2*tid],S.a_[2*tid+1]);
    __syncthreads();

    // ---- cc (own i-slice; uq streamed) ----
    {
      int i=tid>>3, q8=tid&7;
      float acc=0.f;
      const unsigned* up = uqP + ((size_t)b*512 + s*128)*128 + (size_t)i*128;
      #pragma unroll 4
      for(int kk=0;kk<16;kk++){
        int qp=kk*8+q8;
        acc=DOT2(S.a2[qp], up[qp], acc);
      }
      acc+=__shfl_xor(acc,1,64); acc+=__shfl_xor(acc,2,64); acc+=__shfl_xor(acc,4,64);
      if(q8==0) S.ccf[i]=acc;
    }
    // ---- Gc = a.M (LDS) ----
    {
      int jl=tid>>2, qc=tid&3;
      float acc=0.f;
      #pragma unroll 8
      for(int kk=0;kk<32;kk++){
        int qp=kk*4+qc;
        acc=DOT2(S.a2[qp], S.M[qp*257+jl], acc);
      }
      acc+=__shfl_xor(acc,1,64); acc+=__shfl_xor(acc,2,64);
      if(qc==0) S.Gc[jl]=acc;
    }
    __syncthreads();
    if(tid<256){
      h2 gv=uh(S.gupl[tid>>1]);
      float g=sigm(S.Gc[tid]+(float)gv[tid&1]);
      S.c_f[tid]=g*S.ccf[tid&127];
    }
    __syncthreads();
    if(tid<128) S.cpr[tid]=pk(S.c_f[2*tid],S.c_f[2*tid+1]);
    __syncthreads();

    // ---- gi partial (WihT streamed, coalesced in k) ----
    if(kk_<450){
      float acc=0.f;
      #pragma unroll 8
      for(int m=0;m<64;m++){
        int jpg = half_*256 + s*64 + m;
        acc=DOT2(WihTu[(size_t)jpg*456+kk_], S.cpr[half_*64+m], acc);
      }
      S.rgi[half_][kk_]=acc;
    }
    __syncthreads();
    if(tid<225){
      float g0=S.rgi[0][2*tid]+S.rgi[1][2*tid];
      float g1=S.rgi[0][2*tid+1]+S.rgi[1][2*tid+1];
      pubw(giP + myslot + tid, (unsigned)(t+1), pk(g0,g1));
    }
    // ---- gh (off critical path; lands before next GRU's sync) ----
    if(kk_<450){
      float ah=0.f;
      int p0=half_*38, p1=half_?76:38;
      for(int p=p0;p<p1;p++) ah=DOT2(WhhP[p*456+kk_], S.vp[p], ah);
      S.rgh[half_][kk_]=ah;
    }
  }
  // ---- epilogue: v_512 -> dout[511] (s==0 only) ----
  if(s==0){
    if(tid<225){
      int off[4]={gib+tid, gib+226+tid, gib+452+tid, gib+678+tid};
      unsigned gv[4];
      waitN<4>(giP,off,512u,gv,kf);
      float g0=0.f,g1=0.f;
      #pragma unroll
      for(int k=0;k<4;k++){ h2 x=uh(gv[k]); g0+=(float)x[0]; g1+=(float)x[1]; }
      S.gi[2*tid]=g0; S.gi[2*tid+1]=g1;
    }
    __syncthreads();
    if(tid<150){
      float gh0=S.rgh[0][tid]+S.rgh[1][tid]+S.bh[tid];
      float gh1=S.rgh[0][150+tid]+S.rgh[1][150+tid]+S.bh[150+tid];
      float gh2=S.rgh[0][300+tid]+S.rgh[1][300+tid]+S.bh[300+tid];
      float rg=sigm(S.gi[tid]+S.bi[tid] + gh0);
      float zg=sigm(S.gi[150+tid]+S.bi[150+tid] + gh1);
      float ng=ftanh(S.gi[300+tid]+S.bi[300+tid] + rg*gh2);
      dout[((size_t)511*32+b)*150+tid]=fmaf(zg, S.v[tid]-ng, ng);
    }
  }
}

// ---------------- host ----------------
extern "C" void kernel_launch(void* const* d_in, const int* in_sizes, int n_in,
                              void* d_out, int out_size, void* d_ws, size_t ws_size,
                              hipStream_t stream)
{
  const float* up  = (const float*)d_in[0];
  const float* uq  = (const float*)d_in[1];
  const float* v0  = (const float*)d_in[2];
  const float* Vm  = (const float*)d_in[3];
  const float* Wp  = (const float*)d_in[4];
  const float* Wq  = (const float*)d_in[5];
  const float* Wv  = (const float*)d_in[6];
  const float* Wg  = (const float*)d_in[7];
  const float* W_ih= (const float*)d_in[8];
  const float* W_hh= (const float*)d_in[9];
  const float* b_ih= (const float*)d_in[10];
  const float* b_hh= (const float*)d_in[11];
  float* dout = (float*)d_out;
  char* wsb = (char*)d_ws;

  size_t off = 0;
  auto alloc = [&](size_t bytes)->size_t{ size_t p = off; off = (off + bytes + 255) & ~(size_t)255; return p; };
  size_t oWgupT = alloc((size_t)512*1024*4);      // 2MB; comm aliases after gemms
  size_t oWgcT  = alloc((size_t)512*1024*4);
  size_t oWuph  = alloc((size_t)32*512*152*2);
  size_t oWqUqh = alloc((size_t)32*256*152*2);
  size_t oWihT  = alloc((size_t)512*456*4);
  size_t oWhhP  = alloc((size_t)76*456*4);
  size_t oWvU   = alloc((size_t)76*152*4);
  size_t oUqP   = alloc((size_t)32*512*128*4);
  size_t oMp    = alloc((size_t)32*1024*128*4);
  size_t oGup3  = alloc((size_t)32*512*1024*2);   // WpT/WqT alias (dead before write)
  if(ws_size < off) return;

  float*    WgupT = (float*)(wsb + oWgupT);
  float*    WgcT  = (float*)(wsb + oWgcT);
  _Float16* Wuph  = (_Float16*)(wsb + oWuph);
  _Float16* WqUqh = (_Float16*)(wsb + oWqUqh);
  unsigned* WihT  = (unsigned*)(wsb + oWihT);
  unsigned* WhhP  = (unsigned*)(wsb + oWhhP);
  unsigned* WvU   = (unsigned*)(wsb + oWvU);
  unsigned* uqP   = (unsigned*)(wsb + oUqP);
  unsigned* Mp    = (unsigned*)(wsb + oMp);
  _Float16* Gup3  = (_Float16*)(wsb + oGup3);
  float* WpT = (float*)(wsb + oGup3);
  float* WqT = (float*)(wsb + oGup3 + 307456);

  // tagged pubs alias the (dead-after-gemms) WgupT region
  u64t* comm64 = (u64t*)(wsb + oWgupT);
  u64t* giP = comm64;              // 32*4*226 = 28928 u64
  unsigned* kf = (unsigned*)(comm64 + 28928);

  k_fold <<<256,256,0,stream>>>(Wp,Wq,Wg, WpT,WqT,WgupT,WgcT);
  k_fold2<<<256,256,0,stream>>>(W_ih, W_hh, Wv, WihT, WhhP, WvU);
  k_uqp  <<<dim3(32,8),256,0,stream>>>(uq, uqP);
  k_gemm<0><<<dim3(512,1),256,0,stream>>>(up, WpT, Wuph, 150);
  k_gemm<3><<<dim3(256,1),256,0,stream>>>(uq, WqT, WqUqh, 150);
  k_gemm<4><<<dim3(512,4),256,0,stream>>>(up, WgupT, Gup3, 1024);  // WpT/WqT dead now
  k_gemmM<<<dim3(32,8,4),256,0,stream>>>(uq, WgcT, Mp);
  k_init <<<57,1024,0,stream>>>((unsigned*)comm64);                 // WgupT dead now

  int smem = (int)sizeof(SMW);
  hipFuncSetAttribute((const void*)persist, hipFuncAttributeMaxDynamicSharedMemorySize, smem);
  const unsigned* Gup3u  = (const unsigned*)Gup3;
  const unsigned* Wuphu  = (const unsigned*)Wuph;
  const unsigned* WqUqhu = (const unsigned*)WqUqh;
  void* ka[15] = { (void*)&uqP, (void*)&Mp, (void*)&Gup3u, (void*)&Wuphu, (void*)&WqUqhu,
                   (void*)&WihT, (void*)&WhhP, (void*)&WvU,
                   (void*)&v0, (void*)&Vm, (void*)&b_ih, (void*)&b_hh,
                   (void*)&giP, (void*)&kf, (void*)&dout };
  hipLaunchCooperativeKernel((const void*)persist, dim3(128), dim3(1024), ka,
                             (unsigned)smem, stream);
}

// Round 11
// 10631.432 us; speedup vs baseline: 1.8237x; 1.8237x over previous
//
#include <hip/hip_runtime.h>
#include <hip/hip_bf16.h>

#define AGENT __HIP_MEMORY_SCOPE_AGENT
#define RLX __ATOMIC_RELAXED
typedef unsigned long long u64t;

typedef _Float16 h2 __attribute__((ext_vector_type(2)));
union U32H2 { unsigned u; h2 h; };
__device__ __forceinline__ h2 uh(unsigned u){ U32H2 c; c.u=u; return c.h; }
__device__ __forceinline__ unsigned pk(float a, float b){
  U32H2 c; c.h = h2{(_Float16)a, (_Float16)b}; return c.u;
}
#define RCPF(x) __builtin_amdgcn_rcpf(x)

__device__ __forceinline__ float DOT2(unsigned a, unsigned b, float acc){
#if __has_builtin(__builtin_amdgcn_fdot2)
  return __builtin_amdgcn_fdot2(uh(a), uh(b), acc, false);
#else
  h2 x = uh(a), y = uh(b);
  acc = fmaf((float)x[0], (float)y[0], acc);
  return fmaf((float)x[1], (float)y[1], acc);
#endif
}
__device__ __forceinline__ float sigm(float x){ return RCPF(1.0f+__expf(-x)); }
__device__ __forceinline__ float ftanh(float x){ return 1.0f - 2.0f*RCPF(1.0f+__expf(x+x)); }

// ---------- value-tagged pub/poll (relaxed 64-bit agent atomics; R7/R8-proven) ----------
__device__ __forceinline__ void pubw(u64t* p, unsigned seq, unsigned data){
  __hip_atomic_store(p, ((u64t)seq<<32)|(u64t)data, RLX, AGENT);
}
template<int K>
__device__ __forceinline__ void waitN(const u64t* base, const int* off, unsigned seq,
                                      unsigned* out, unsigned* kf){
  long n=0;
  for(;;){
    u64t v[K]; bool ok=true;
    #pragma unroll
    for(int k=0;k<K;k++) v[k]=__hip_atomic_load(base+off[k], RLX, AGENT);
    #pragma unroll
    for(int k=0;k<K;k++) ok &= ((unsigned)(v[k]>>32)==seq);
    if(ok){
      #pragma unroll
      for(int k=0;k<K;k++) out[k]=(unsigned)v[k];
      return;
    }
    __builtin_amdgcn_s_sleep(1);
    if((++n&255)==0){
      if(__hip_atomic_load(kf,RLX,AGENT)!=0u) break;
      if(n>300000L){ __hip_atomic_store(kf,1u,RLX,AGENT); break; }
    }
  }
  #pragma unroll
  for(int k=0;k<K;k++) out[k]=0u;
}

// ---------------- one-time weight folds (f32 GEMM inputs) ----------------
__global__ void k_fold(const float* __restrict__ Wp, const float* __restrict__ Wq,
                       const float* __restrict__ Wg,
                       float* __restrict__ WpT, float* __restrict__ WqT,
                       float* __restrict__ WgupT, float* __restrict__ WgcT)
{
  int i0 = blockIdx.x*blockDim.x+threadIdx.x;
  int st = gridDim.x*blockDim.x;
  for(int o=i0;o<512*150;o+=st){ int h=o%150, i=o/150;
    WpT[o]=Wp[h*1024+i]+Wp[h*1024+512+i];
    WqT[o]=Wq[h*1024+i]+Wq[h*1024+512+i]; }
  for(int o=i0;o<512*1024;o+=st){ int i=o&511, j=o>>9;
    size_t rb=(size_t)(1024+j)*2048;
    WgupT[(size_t)i*1024+j]=Wg[rb+i]+Wg[rb+512+i];
    WgcT [(size_t)i*1024+j]=Wg[rb+1024+i]+Wg[rb+1536+i]; }
}

// row-major pair layouts: WihKJ[k][512 jp], WhhKP[k][76 p], WvU[p][152 h]
__global__ void k_fold2(const float* __restrict__ Wih,
                        const float* __restrict__ Whh, const float* __restrict__ Wv,
                        unsigned* __restrict__ WihKJ,
                        unsigned* __restrict__ WhhKP, unsigned* __restrict__ WvU)
{
  int i0 = blockIdx.x*blockDim.x+threadIdx.x;
  int st = gridDim.x*blockDim.x;
  for(int o=i0;o<450*512;o+=st){ int jp=o&511, k=o>>9;
    WihKJ[o] = pk(Wih[(size_t)k*1024+2*jp], Wih[(size_t)k*1024+2*jp+1]); }
  for(int o=i0;o<450*76;o+=st){ int p=o%76, k=o/76;
    float x = (2*p<150)? Whh[k*150+2*p] : 0.f;
    float y = (2*p+1<150)? Whh[k*150+2*p+1] : 0.f;
    WhhKP[o]=pk(x,y); }
  for(int o=i0;o<76*152;o+=st){ int h=o%152, p=o/152;
    float x=0.f,y=0.f;
    if(h<150){ if(2*p<150) x=Wv[h*150+2*p]; if(2*p+1<150) y=Wv[h*150+2*p+1]; }
    WvU[o]=pk(x,y); }
}

// uq (q,b,i) f32 -> uqP[(b*512+i)*128 + qp] pairs over q
__global__ __launch_bounds__(256) void k_uqp(const float* __restrict__ uq, unsigned* __restrict__ uqP){
  __shared__ float Al[32*512];
  int b = blockIdx.x, qt = blockIdx.y, tid = threadIdx.x;
  for(int o4=tid;o4<4096;o4+=256){ int m=o4>>7, i4=o4&127;
    ((float4*)Al)[o4] = *(const float4*)&uq[(size_t)(qt*32+m)*16384 + b*512 + i4*4]; }
  __syncthreads();
  for(int o=tid;o<8192;o+=256){ int i=o>>4, p=o&15;
    uqP[((size_t)b*512+i)*128 + qt*16 + p] = pk(Al[(2*p)*512+i], Al[(2*p+1)*512+i]); }
}

// precompute GEMMs: MODE0 Wuph[b][t][152] ; MODE3 WqUqh[b][q][152] ; MODE4 Gup3[b][t][1024]
template<int MODE>
__global__ __launch_bounds__(256) void k_gemm(const float* __restrict__ A,
   const float* __restrict__ WT, _Float16* __restrict__ oH, int N)
{
  __shared__ float Al[32*512];
  int mt=blockIdx.x, nt=blockIdx.y, tid=threadIdx.x;
  const float* Ab = A + (size_t)mt*16384;
  for(int o=tid;o<4096;o+=256) ((float4*)Al)[o]=((const float4*)Ab)[o];
  __syncthreads();
  int n = nt*256+tid;
  if(n>=N) return;
  float acc[32];
  #pragma unroll
  for(int m=0;m<32;m++) acc[m]=0.f;
  const float* wp = WT + n;
  #pragma unroll 2
  for(int k=0;k<512;k+=2){
    float w0 = wp[(size_t)k*N], w1 = wp[(size_t)(k+1)*N];
    #pragma unroll
    for(int m=0;m<32;m++) acc[m]=fmaf(w0, Al[m*512+k], acc[m]);
    #pragma unroll
    for(int m=0;m<32;m++) acc[m]=fmaf(w1, Al[m*512+k+1], acc[m]);
  }
  if(MODE==0){
    #pragma unroll
    for(int m=0;m<32;m++) oH[((size_t)m*512 + mt)*152 + n] = (_Float16)acc[m];
  } else if(MODE==3){
    #pragma unroll
    for(int m=0;m<32;m++) oH[((size_t)m*256 + mt)*152 + n] = (_Float16)acc[m];
  } else {
    #pragma unroll
    for(int m=0;m<32;m++) oH[((size_t)m*512 + mt)*1024 + n] = (_Float16)acc[m];
  }
}

// M[b] = uq[b] @ WgcT : Mp[(b*1024+j)*128 + qp]
__global__ __launch_bounds__(256) void k_gemmM(const float* __restrict__ uq,
   const float* __restrict__ WgcT, unsigned* __restrict__ Mp)
{
  __shared__ float Al[32*512];
  int b=blockIdx.x, qt=blockIdx.y, nt=blockIdx.z, tid=threadIdx.x;
  for(int o4=tid;o4<4096;o4+=256){ int m=o4>>7, i4=o4&127;
    ((float4*)Al)[o4] = *(const float4*)&uq[(size_t)(qt*32+m)*16384 + b*512 + i4*4]; }
  __syncthreads();
  int n = nt*256+tid;
  float acc[32];
  #pragma unroll
  for(int m=0;m<32;m++) acc[m]=0.f;
  const float* wp = WgcT + n;
  #pragma unroll 2
  for(int k=0;k<512;k+=2){
    float w0 = wp[(size_t)k*1024], w1 = wp[(size_t)(k+1)*1024];
    #pragma unroll
    for(int m=0;m<32;m++) acc[m]=fmaf(w0, Al[m*512+k], acc[m]);
    #pragma unroll
    for(int m=0;m<32;m++) acc[m]=fmaf(w1, Al[m*512+k+1], acc[m]);
  }
  #pragma unroll
  for(int p=0;p<16;p++)
    Mp[((size_t)b*1024 + n)*128 + qt*16 + p] = pk(acc[2*p], acc[2*p+1]);
}

__global__ void k_init(unsigned* comm){
  int i = blockIdx.x*blockDim.x + threadIdx.x;
  if(i < 66052) comm[i] = 0u;
}

// ---------------- persistent: 160 blocks, 2-hop, conflict/stream-tuned ----------------
struct __align__(16) SMO {
  unsigned WvU[76*152];
  unsigned WqUq[256*76];
  unsigned wup[80], vp[80];
  float V[152], v[152], w2[152], s[256], a[256];
  float gi[452], rgh[2][452], bi[452], bh[452];
};
struct __align__(16) SMW {
  unsigned M[128*265];         // [qp][jl] stride 265 (265%32=9 -> ~2-way banks)
  unsigned a2[128], gup[128], cpr[128];
  float ccf[128], Gc[256], c_f[256], rgi[2][452];
};
union SMU { SMO o; SMW w; };

__global__ __launch_bounds__(1024) void persist(
  const unsigned* __restrict__ uqP,   const unsigned* __restrict__ Mp,
  const unsigned* __restrict__ Gup3u, const unsigned* __restrict__ Wuphu,
  const unsigned* __restrict__ WqUqhu, const unsigned* __restrict__ WihKJ,
  const unsigned* __restrict__ WhhKP,  const unsigned* __restrict__ WvUg,
  const float* __restrict__ v0, const float* __restrict__ Vin,
  const float* __restrict__ bih, const float* __restrict__ bhh,
  u64t* aP, u64t* giP, unsigned* kf,
  float* __restrict__ dout)
{
  extern __shared__ char smraw[];
  SMU& S = *reinterpret_cast<SMU*>(smraw);
  const int tid = threadIdx.x;
  const int bid = blockIdx.x;

  if(bid < 32){
    // ================= OWNER (per b): GRU + gh, w2, s, softmax -> aP =================
    const int b = bid;
    for(int o=tid;o<11552;o+=1024) S.o.WvU[o]=WvUg[o];
    for(int o=tid;o<19456;o+=1024){ int q=o/76,w=o%76;
      S.o.WqUq[o]=WqUqhu[((size_t)b*256+q)*76+w]; }
    for(int o=tid;o<152;o+=1024){
      S.o.V[o]=(o<150)?Vin[b*150+o]:0.f;
      S.o.v[o]=(o<150)?v0[b*150+o]:0.f; }
    for(int o=tid;o<452;o+=1024){
      S.o.bi[o]=(o<450)?bih[o]:0.f;
      S.o.bh[o]=(o<450)?bhh[o]:0.f; }
    __syncthreads();

    const int gib = b*904;   // u64 index; layout [word 0..225][slot 0..3] interleaved
    for(int t=0;t<512;++t){
      if(tid<76) S.o.wup[tid]=Wuphu[((size_t)b*512+t)*76+tid];
      if(t>0){
        if(tid<225){
          int off[4]={gib+tid*4, gib+tid*4+1, gib+tid*4+2, gib+tid*4+3};
          unsigned gv[4];
          waitN<4>(giP,off,(unsigned)t,gv,kf);
          float g0=0.f,g1=0.f;
          #pragma unroll
          for(int k=0;k<4;k++){ h2 x=uh(gv[k]); g0+=(float)x[0]; g1+=(float)x[1]; }
          S.o.gi[2*tid]=g0; S.o.gi[2*tid+1]=g1;
        }
        __syncthreads();
        if(tid<150){
          float gh0=S.o.rgh[0][tid]+S.o.rgh[1][tid]+S.o.bh[tid];
          float gh1=S.o.rgh[0][150+tid]+S.o.rgh[1][150+tid]+S.o.bh[150+tid];
          float gh2=S.o.rgh[0][300+tid]+S.o.rgh[1][300+tid]+S.o.bh[300+tid];
          float rg=sigm(S.o.gi[tid]+S.o.bi[tid] + gh0);
          float zg=sigm(S.o.gi[150+tid]+S.o.bi[150+tid] + gh1);
          float ng=ftanh(S.o.gi[300+tid]+S.o.bi[300+tid] + rg*gh2);
          float vn=fmaf(zg, S.o.v[tid]-ng, ng);
          S.o.v[tid]=vn;
          dout[((size_t)(t-1)*32+b)*150+tid]=vn;
        }
        __syncthreads();
      }
      if(tid<76) S.o.vp[tid]=pk(S.o.v[2*tid], S.o.v[2*tid+1]);
      __syncthreads();
      // w2 = wup + Wv.v (LDS)
      if(tid<608){
        int h=tid>>2, qd=tid&3;
        float acc=0.f;
        if(h<150){
          #pragma unroll
          for(int p=qd*19;p<qd*19+19;p++) acc=DOT2(S.o.WvU[p*152+h], S.o.vp[p], acc);
        }
        acc+=__shfl_xor(acc,1,64); acc+=__shfl_xor(acc,2,64);
        if(h<150&&qd==0){ h2 ww=uh(S.o.wup[h>>1]); S.o.w2[h]=acc+(float)ww[h&1]; }
      }
      __syncthreads();
      // s[q] = sum_h V[h] tanh(w2[h]+WqUq[q,h]) (LDS)
      {
        int q=tid>>2, hq=tid&3;
        int hp0=hq*19, hp1=(hq==3)?75:hp0+19;
        float acc=0.f;
        for(int hp=hp0;hp<hp1;hp++){
          h2 wp=uh(S.o.WqUq[q*76+hp]);
          acc=fmaf(S.o.V[2*hp],   ftanh(S.o.w2[2*hp]  +(float)wp[0]), acc);
          acc=fmaf(S.o.V[2*hp+1], ftanh(S.o.w2[2*hp+1]+(float)wp[1]), acc);
        }
        acc+=__shfl_xor(acc,1,64); acc+=__shfl_xor(acc,2,64);
        if(hq==0) S.o.s[q]=acc;
      }
      __syncthreads();
      if(tid<64){
        float x0=S.o.s[tid],x1=S.o.s[tid+64],x2=S.o.s[tid+128],x3=S.o.s[tid+192];
        float mx=fmaxf(fmaxf(x0,x1),fmaxf(x2,x3));
        #pragma unroll
        for(int o=1;o<64;o<<=1) mx=fmaxf(mx,__shfl_xor(mx,o,64));
        float e0=__expf(x0-mx),e1=__expf(x1-mx),e2=__expf(x2-mx),e3=__expf(x3-mx);
        float sm=e0+e1+e2+e3;
        #pragma unroll
        for(int o=1;o<64;o<<=1) sm+=__shfl_xor(sm,o,64);
        float rs=RCPF(sm);
        S.o.a[tid]=e0*rs; S.o.a[tid+64]=e1*rs; S.o.a[tid+128]=e2*rs; S.o.a[tid+192]=e3*rs;
      }
      __syncthreads();
      if(tid<128) pubw(aP+b*128+tid,(unsigned)(t+1), pk(S.o.a[2*tid],S.o.a[2*tid+1]));
      // gh = Whh.v row-major stream (off critical path, overlaps worker phase)
      {
        int k=tid&511, half=tid>>9;
        if(k<450){
          const unsigned* wh = WhhKP + (size_t)k*76 + half*38;
          float ah=0.f;
          #pragma unroll
          for(int p=0;p<38;p++) ah=DOT2(wh[p], S.o.vp[half*38+p], ah);
          S.o.rgh[half][k]=ah;
        }
      }
      // rgh consumed after next iteration's post-poll __syncthreads
    }
    // epilogue: v_512 -> dout[511]
    if(tid<225){
      int off[4]={gib+tid*4, gib+tid*4+1, gib+tid*4+2, gib+tid*4+3};
      unsigned gv[4];
      waitN<4>(giP,off,512u,gv,kf);
      float g0=0.f,g1=0.f;
      #pragma unroll
      for(int k=0;k<4;k++){ h2 x=uh(gv[k]); g0+=(float)x[0]; g1+=(float)x[1]; }
      S.o.gi[2*tid]=g0; S.o.gi[2*tid+1]=g1;
    }
    __syncthreads();
    if(tid<150){
      float gh0=S.o.rgh[0][tid]+S.o.rgh[1][tid]+S.o.bh[tid];
      float gh1=S.o.rgh[0][150+tid]+S.o.rgh[1][150+tid]+S.o.bh[150+tid];
      float gh2=S.o.rgh[0][300+tid]+S.o.rgh[1][300+tid]+S.o.bh[300+tid];
      float rg=sigm(S.o.gi[tid]+S.o.bi[tid] + gh0);
      float zg=sigm(S.o.gi[150+tid]+S.o.bi[150+tid] + gh1);
      float ng=ftanh(S.o.gi[300+tid]+S.o.bi[300+tid] + rg*gh2);
      dout[((size_t)511*32+b)*150+tid]=fmaf(zg, S.o.v[tid]-ng, ng);
    }

  } else {
    // ================= WORKER (4 per b): cc, Gc=a.M, gate, c_, gi partial =================
    const int wid = bid-32;
    const int b = wid>>2, s = wid&3;
    for(int o=tid;o<32768;o+=1024){
      int qp=o&127, jl=o>>7;
      int j = s*128 + (jl&127) + ((jl>>7)<<9);
      S.w.M[qp*265+jl] = Mp[((size_t)b*1024+j)*128+qp];
    }
    __syncthreads();
    const int gib = b*904;
    for(int t=0;t<512;++t){
      if(tid<128){
        int wi = (tid<64)? (s*64+tid) : (256+s*64+tid-64);
        S.w.gup[tid] = Gup3u[((size_t)b*512+t)*512 + wi];
      }
      if(tid<128){
        int off[1]={b*128+tid};
        unsigned av[1];
        waitN<1>(aP,off,(unsigned)(t+1),av,kf);
        S.w.a2[tid]=av[0];
      }
      __syncthreads();
      // cc[i] = sum_qp dot2(a2, uq[i])  (uint4 row loads, L1-friendly)
      {
        int i=tid>>3, q8=tid&7;
        float acc=0.f;
        const uint4* up4 = (const uint4*)(uqP + ((size_t)b*512 + s*128 + i)*128 + q8*16);
        #pragma unroll
        for(int c4=0;c4<4;c4++){
          uint4 u = up4[c4];
          int qb = q8*16 + c4*4;
          acc=DOT2(S.w.a2[qb],u.x,acc); acc=DOT2(S.w.a2[qb+1],u.y,acc);
          acc=DOT2(S.w.a2[qb+2],u.z,acc); acc=DOT2(S.w.a2[qb+3],u.w,acc);
        }
        acc+=__shfl_xor(acc,1,64); acc+=__shfl_xor(acc,2,64); acc+=__shfl_xor(acc,4,64);
        if(q8==0) S.w.ccf[i]=acc;
      }
      // Gc[jl] = sum_qp dot2(a2, M[qp][jl])  (stride-265 LDS)
      {
        int jl=tid>>2, qc=tid&3;
        float acc=0.f;
        #pragma unroll 8
        for(int kk=0;kk<32;kk++){
          int qp=kk*4+qc;
          acc=DOT2(S.w.a2[qp], S.w.M[qp*265+jl], acc);
        }
        acc+=__shfl_xor(acc,1,64); acc+=__shfl_xor(acc,2,64);
        if(qc==0) S.w.Gc[jl]=acc;
      }
      __syncthreads();
      if(tid<256){
        h2 gv=uh(S.w.gup[tid>>1]);
        float g=sigm(S.w.Gc[tid]+(float)gv[tid&1]);
        S.w.c_f[tid]=g*S.w.ccf[tid&127];
      }
      __syncthreads();
      if(tid<128) S.w.cpr[tid]=pk(S.w.c_f[2*tid],S.w.c_f[2*tid+1]);
      __syncthreads();
      // gi partial: row-major WihKJ, uint4 loads (2 L1 misses + 14 hits per thread)
      {
        int k=tid&511, half=tid>>9;
        if(k<450){
          const uint4* wr = (const uint4*)(WihKJ + (size_t)k*512 + half*256 + s*64);
          float acc=0.f;
          #pragma unroll
          for(int m4=0;m4<16;m4++){
            uint4 w = wr[m4];
            int mb = half*64 + m4*4;
            acc=DOT2(w.x,S.w.cpr[mb],acc);   acc=DOT2(w.y,S.w.cpr[mb+1],acc);
            acc=DOT2(w.z,S.w.cpr[mb+2],acc); acc=DOT2(w.w,S.w.cpr[mb+3],acc);
          }
          S.w.rgi[half][k]=acc;
        }
      }
      __syncthreads();
      if(tid<225){
        float g0=S.w.rgi[0][2*tid]+S.w.rgi[1][2*tid];
        float g1=S.w.rgi[0][2*tid+1]+S.w.rgi[1][2*tid+1];
        pubw(giP + gib + tid*4 + s, (unsigned)(t+1), pk(g0,g1));
      }
    }
  }
}

// ---------------- host ----------------
extern "C" void kernel_launch(void* const* d_in, const int* in_sizes, int n_in,
                              void* d_out, int out_size, void* d_ws, size_t ws_size,
                              hipStream_t stream)
{
  const float* up  = (const float*)d_in[0];
  const float* uq  = (const float*)d_in[1];
  const float* v0  = (const float*)d_in[2];
  const float* Vm  = (const float*)d_in[3];
  const float* Wp  = (const float*)d_in[4];
  const float* Wq  = (const float*)d_in[5];
  const float* Wv  = (const float*)d_in[6];
  const float* Wg  = (const float*)d_in[7];
  const float* W_ih= (const float*)d_in[8];
  const float* W_hh= (const float*)d_in[9];
  const float* b_ih= (const float*)d_in[10];
  const float* b_hh= (const float*)d_in[11];
  float* dout = (float*)d_out;
  char* wsb = (char*)d_ws;

  size_t off = 0;
  auto alloc = [&](size_t bytes)->size_t{ size_t p = off; off = (off + bytes + 255) & ~(size_t)255; return p; };
  size_t oWgupT = alloc((size_t)512*1024*4);      // 2MB; comm aliases after gemms
  size_t oWgcT  = alloc((size_t)512*1024*4);
  size_t oWuph  = alloc((size_t)32*512*152*2);
  size_t oWqUqh = alloc((size_t)32*256*152*2);
  size_t oWihKJ = alloc((size_t)450*512*4);
  size_t oWhhKP = alloc((size_t)450*76*4);
  size_t oWvU   = alloc((size_t)76*152*4);
  size_t oUqP   = alloc((size_t)32*512*128*4);
  size_t oMp    = alloc((size_t)32*1024*128*4);
  size_t oGup3  = alloc((size_t)32*512*1024*2);   // WpT/WqT alias (dead before write)
  if(ws_size < off) return;

  float*    WgupT = (float*)(wsb + oWgupT);
  float*    WgcT  = (float*)(wsb + oWgcT);
  _Float16* Wuph  = (_Float16*)(wsb + oWuph);
  _Float16* WqUqh = (_Float16*)(wsb + oWqUqh);
  unsigned* WihKJ = (unsigned*)(wsb + oWihKJ);
  unsigned* WhhKP = (unsigned*)(wsb + oWhhKP);
  unsigned* WvU   = (unsigned*)(wsb + oWvU);
  unsigned* uqP   = (unsigned*)(wsb + oUqP);
  unsigned* Mp    = (unsigned*)(wsb + oMp);
  _Float16* Gup3  = (_Float16*)(wsb + oGup3);
  float* WpT = (float*)(wsb + oGup3);
  float* WqT = (float*)(wsb + oGup3 + 307456);

  // tagged pubs alias the (dead-after-gemms) WgupT region
  u64t* comm64 = (u64t*)(wsb + oWgupT);
  u64t* aP  = comm64;              // 32*128 = 4096
  u64t* giP = comm64 + 4096;       // 32*904 = 28928 (interleaved [word][slot])
  unsigned* kf = (unsigned*)(comm64 + 33024);

  k_fold <<<256,256,0,stream>>>(Wp,Wq,Wg, WpT,WqT,WgupT,WgcT);
  k_fold2<<<256,256,0,stream>>>(W_ih, W_hh, Wv, WihKJ, WhhKP, WvU);
  k_uqp  <<<dim3(32,8),256,0,stream>>>(uq, uqP);
  k_gemm<0><<<dim3(512,1),256,0,stream>>>(up, WpT, Wuph, 150);
  k_gemm<3><<<dim3(256,1),256,0,stream>>>(uq, WqT, WqUqh, 150);
  k_gemm<4><<<dim3(512,4),256,0,stream>>>(up, WgupT, Gup3, 1024);  // WpT/WqT dead now
  k_gemmM<<<dim3(32,8,4),256,0,stream>>>(uq, WgcT, Mp);
  k_init <<<65,1024,0,stream>>>((unsigned*)comm64);                 // WgupT dead now

  int smem = (int)sizeof(SMU);
  hipFuncSetAttribute((const void*)persist, hipFuncAttributeMaxDynamicSharedMemorySize, smem);
  const unsigned* Gup3u  = (const unsigned*)Gup3;
  const unsigned* Wuphu  = (const unsigned*)Wuph;
  const unsigned* WqUqhu = (const unsigned*)WqUqh;
  void* ka[16] = { (void*)&uqP, (void*)&Mp, (void*)&Gup3u, (void*)&Wuphu, (void*)&WqUqhu,
                   (void*)&WihKJ, (void*)&WhhKP, (void*)&WvU,
                   (void*)&v0, (void*)&Vm, (void*)&b_ih, (void*)&b_hh,
                   (void*)&aP, (void*)&giP, (void*)&kf, (void*)&dout };
  hipLaunchCooperativeKernel((const void*)persist, dim3(160), dim3(1024), ka,
                             (unsigned)smem, stream);
}

// Round 12
// 6872.742 us; speedup vs baseline: 2.8211x; 1.5469x over previous
//
#include <hip/hip_runtime.h>
#include <hip/hip_bf16.h>

#define AGENT __HIP_MEMORY_SCOPE_AGENT
#define RLX __ATOMIC_RELAXED
typedef unsigned long long u64t;

typedef _Float16 h2 __attribute__((ext_vector_type(2)));
union U32H2 { unsigned u; h2 h; };
__device__ __forceinline__ h2 uh(unsigned u){ U32H2 c; c.u=u; return c.h; }
__device__ __forceinline__ unsigned pk(float a, float b){
  U32H2 c; c.h = h2{(_Float16)a, (_Float16)b}; return c.u;
}
#define RCPF(x) __builtin_amdgcn_rcpf(x)

__device__ __forceinline__ float DOT2(unsigned a, unsigned b, float acc){
#if __has_builtin(__builtin_amdgcn_fdot2)
  return __builtin_amdgcn_fdot2(uh(a), uh(b), acc, false);
#else
  h2 x = uh(a), y = uh(b);
  acc = fmaf((float)x[0], (float)y[0], acc);
  return fmaf((float)x[1], (float)y[1], acc);
#endif
}
__device__ __forceinline__ float sigm(float x){ return RCPF(1.0f+__expf(-x)); }
__device__ __forceinline__ float ftanh(float x){ return 1.0f - 2.0f*RCPF(1.0f+__expf(x+x)); }

// ---------- value-tagged pub/poll (relaxed 64-bit agent atomics; R7/R8-proven) ----------
__device__ __forceinline__ void pubw(u64t* p, unsigned seq, unsigned data){
  __hip_atomic_store(p, ((u64t)seq<<32)|(u64t)data, RLX, AGENT);
}
template<int K>
__device__ __forceinline__ void waitN(const u64t* base, const int* off, unsigned seq,
                                      unsigned* out, unsigned* kf){
  long n=0;
  for(;;){
    u64t v[K]; bool ok=true;
    #pragma unroll
    for(int k=0;k<K;k++) v[k]=__hip_atomic_load(base+off[k], RLX, AGENT);
    #pragma unroll
    for(int k=0;k<K;k++) ok &= ((unsigned)(v[k]>>32)==seq);
    if(ok){
      #pragma unroll
      for(int k=0;k<K;k++) out[k]=(unsigned)v[k];
      return;
    }
    __builtin_amdgcn_s_sleep(1);
    if((++n&255)==0){
      if(__hip_atomic_load(kf,RLX,AGENT)!=0u) break;
      if(n>300000L){ __hip_atomic_store(kf,1u,RLX,AGENT); break; }
    }
  }
  #pragma unroll
  for(int k=0;k<K;k++) out[k]=0u;
}

// ---------------- one-time weight folds (f32 GEMM inputs) ----------------
__global__ void k_fold(const float* __restrict__ Wp, const float* __restrict__ Wq,
                       const float* __restrict__ Wg,
                       float* __restrict__ WpT, float* __restrict__ WqT,
                       float* __restrict__ WgupT, float* __restrict__ WgcT)
{
  int i0 = blockIdx.x*blockDim.x+threadIdx.x;
  int st = gridDim.x*blockDim.x;
  for(int o=i0;o<512*150;o+=st){ int h=o%150, i=o/150;
    WpT[o]=Wp[h*1024+i]+Wp[h*1024+512+i];
    WqT[o]=Wq[h*1024+i]+Wq[h*1024+512+i]; }
  for(int o=i0;o<512*1024;o+=st){ int i=o&511, j=o>>9;
    size_t rb=(size_t)(1024+j)*2048;
    WgupT[(size_t)i*1024+j]=Wg[rb+i]+Wg[rb+512+i];
    WgcT [(size_t)i*1024+j]=Wg[rb+1024+i]+Wg[rb+1536+i]; }
}

// pair layouts: WihT[jp*456+k] (COLUMN layout: lane=k coalesced), WhhP[p*456+k], WvU[p*152+h]
__global__ void k_fold2(const float* __restrict__ Wih,
                        const float* __restrict__ Whh, const float* __restrict__ Wv,
                        unsigned* __restrict__ WihT,
                        unsigned* __restrict__ WhhP, unsigned* __restrict__ WvU)
{
  int i0 = blockIdx.x*blockDim.x+threadIdx.x;
  int st = gridDim.x*blockDim.x;
  for(int o=i0;o<512*456;o+=st){ int k=o%456, jp=o/456;
    unsigned v = 0u;
    if(k<450) v = pk(Wih[(size_t)k*1024+2*jp], Wih[(size_t)k*1024+2*jp+1]);
    WihT[o] = v; }
  for(int o=i0;o<76*456;o+=st){ int k=o%456, p=o/456;
    float x=0.f,y=0.f;
    if(k<450){ if(2*p<150) x=Whh[k*150+2*p]; if(2*p+1<150) y=Whh[k*150+2*p+1]; }
    WhhP[o]=pk(x,y); }
  for(int o=i0;o<76*152;o+=st){ int h=o%152, p=o/152;
    float x=0.f,y=0.f;
    if(h<150){ if(2*p<150) x=Wv[h*150+2*p]; if(2*p+1<150) y=Wv[h*150+2*p+1]; }
    WvU[o]=pk(x,y); }
}

// uq (q,b,i) f32 -> uqP[(b*512+i)*128 + qp] pairs over q
__global__ __launch_bounds__(256) void k_uqp(const float* __restrict__ uq, unsigned* __restrict__ uqP){
  __shared__ float Al[32*512];
  int b = blockIdx.x, qt = blockIdx.y, tid = threadIdx.x;
  for(int o4=tid;o4<4096;o4+=256){ int m=o4>>7, i4=o4&127;
    ((float4*)Al)[o4] = *(const float4*)&uq[(size_t)(qt*32+m)*16384 + b*512 + i4*4]; }
  __syncthreads();
  for(int o=tid;o<8192;o+=256){ int i=o>>4, p=o&15;
    uqP[((size_t)b*512+i)*128 + qt*16 + p] = pk(Al[(2*p)*512+i], Al[(2*p+1)*512+i]); }
}

// precompute GEMMs: MODE0 Wuph[b][t][152] ; MODE3 WqUqh[b][q][152] ; MODE4 Gup3[b][t][1024]
template<int MODE>
__global__ __launch_bounds__(256) void k_gemm(const float* __restrict__ A,
   const float* __restrict__ WT, _Float16* __restrict__ oH, int N)
{
  __shared__ float Al[32*512];
  int mt=blockIdx.x, nt=blockIdx.y, tid=threadIdx.x;
  const float* Ab = A + (size_t)mt*16384;
  for(int o=tid;o<4096;o+=256) ((float4*)Al)[o]=((const float4*)Ab)[o];
  __syncthreads();
  int n = nt*256+tid;
  if(n>=N) return;
  float acc[32];
  #pragma unroll
  for(int m=0;m<32;m++) acc[m]=0.f;
  const float* wp = WT + n;
  #pragma unroll 2
  for(int k=0;k<512;k+=2){
    float w0 = wp[(size_t)k*N], w1 = wp[(size_t)(k+1)*N];
    #pragma unroll
    for(int m=0;m<32;m++) acc[m]=fmaf(w0, Al[m*512+k], acc[m]);
    #pragma unroll
    for(int m=0;m<32;m++) acc[m]=fmaf(w1, Al[m*512+k+1], acc[m]);
  }
  if(MODE==0){
    #pragma unroll
    for(int m=0;m<32;m++) oH[((size_t)m*512 + mt)*152 + n] = (_Float16)acc[m];
  } else if(MODE==3){
    #pragma unroll
    for(int m=0;m<32;m++) oH[((size_t)m*256 + mt)*152 + n] = (_Float16)acc[m];
  } else {
    #pragma unroll
    for(int m=0;m<32;m++) oH[((size_t)m*512 + mt)*1024 + n] = (_Float16)acc[m];
  }
}

// M[b] = uq[b] @ WgcT : Mp[(b*1024+j)*128 + qp]
__global__ __launch_bounds__(256) void k_gemmM(const float* __restrict__ uq,
   const float* __restrict__ WgcT, unsigned* __restrict__ Mp)
{
  __shared__ float Al[32*512];
  int b=blockIdx.x, qt=blockIdx.y, nt=blockIdx.z, tid=threadIdx.x;
  for(int o4=tid;o4<4096;o4+=256){ int m=o4>>7, i4=o4&127;
    ((float4*)Al)[o4] = *(const float4*)&uq[(size_t)(qt*32+m)*16384 + b*512 + i4*4]; }
  __syncthreads();
  int n = nt*256+tid;
  float acc[32];
  #pragma unroll
  for(int m=0;m<32;m++) acc[m]=0.f;
  const float* wp = WgcT + n;
  #pragma unroll 2
  for(int k=0;k<512;k+=2){
    float w0 = wp[(size_t)k*1024], w1 = wp[(size_t)(k+1)*1024];
    #pragma unroll
    for(int m=0;m<32;m++) acc[m]=fmaf(w0, Al[m*512+k], acc[m]);
    #pragma unroll
    for(int m=0;m<32;m++) acc[m]=fmaf(w1, Al[m*512+k+1], acc[m]);
  }
  #pragma unroll
  for(int p=0;p<16;p++)
    Mp[((size_t)b*1024 + n)*128 + qt*16 + p] = pk(acc[2*p], acc[2*p+1]);
}

__global__ void k_init(unsigned* comm){
  int i = blockIdx.x*blockDim.x + threadIdx.x;
  if(i < 66052) comm[i] = 0u;
}

// ---------------- persistent: 160 blocks, 2-hop, reduced-barrier ----------------
struct __align__(16) SMO {
  unsigned WvU[76*152];
  unsigned WqUq[256*76];
  unsigned wup[80], vp[80];
  float V[152], v[152], w2[152], s[256];
  float gi[452], rgh[2][452], bi[452], bh[452];
};
struct __align__(16) SMW {
  unsigned M[128*265];         // [qp][jl] stride 265 (265%32=9 -> ~2-way banks)
  unsigned a2[128], gup[128], cpr[128];
  float ccf[128], Gc[256], rgi[2][452];
};
union SMU { SMO o; SMW w; };

__global__ __launch_bounds__(1024) void persist(
  const unsigned* __restrict__ uqP,   const unsigned* __restrict__ Mp,
  const unsigned* __restrict__ Gup3u, const unsigned* __restrict__ Wuphu,
  const unsigned* __restrict__ WqUqhu, const unsigned* __restrict__ WihTu,
  const unsigned* __restrict__ WhhP,  const unsigned* __restrict__ WvUg,
  const float* __restrict__ v0, const float* __restrict__ Vin,
  const float* __restrict__ bih, const float* __restrict__ bhh,
  u64t* aP, u64t* giP, unsigned* kf,
  float* __restrict__ dout)
{
  extern __shared__ char smraw[];
  SMU& S = *reinterpret_cast<SMU*>(smraw);
  const int tid = threadIdx.x;
  const int bid = blockIdx.x;

  if(bid < 32){
    // ================= OWNER (per b): GRU + gh, w2, s, softmax -> aP =================
    const int b = bid;
    for(int o=tid;o<11552;o+=1024) S.o.WvU[o]=WvUg[o];
    for(int o=tid;o<19456;o+=1024){ int q=o/76,w=o%76;
      S.o.WqUq[o]=WqUqhu[((size_t)b*256+q)*76+w]; }
    for(int o=tid;o<152;o+=1024){
      S.o.V[o]=(o<150)?Vin[b*150+o]:0.f;
      S.o.v[o]=(o<150)?v0[b*150+o]:0.f; }
    for(int o=tid;o<452;o+=1024){
      S.o.bi[o]=(o<450)?bih[o]:0.f;
      S.o.bh[o]=(o<450)?bhh[o]:0.f; }
    __syncthreads();
    if(tid<76) S.o.vp[tid]=pk(S.o.v[2*tid], S.o.v[2*tid+1]);
    __syncthreads();

    const int gib = b*904;   // u64 index; [b][slot 0..3][word 0..225]
    for(int t=0;t<512;++t){
      if(tid<76) S.o.wup[tid]=Wuphu[((size_t)b*512+t)*76+tid];
      if(t>0){
        if(tid<225){
          int off[4]={gib+tid, gib+226+tid, gib+452+tid, gib+678+tid};
          unsigned gv[4];
          waitN<4>(giP,off,(unsigned)t,gv,kf);
          float g0=0.f,g1=0.f;
          #pragma unroll
          for(int k=0;k<4;k++){ h2 x=uh(gv[k]); g0+=(float)x[0]; g1+=(float)x[1]; }
          S.o.gi[2*tid]=g0; S.o.gi[2*tid+1]=g1;
        }
        __syncthreads();                         // bar1: gi ready
        if(tid<75){                              // GRU + vp merged (2 h per thread)
          int h0=2*tid, h1=h0+1;
          float gh00=S.o.rgh[0][h0]+S.o.rgh[1][h0]+S.o.bh[h0];
          float gh10=S.o.rgh[0][150+h0]+S.o.rgh[1][150+h0]+S.o.bh[150+h0];
          float gh20=S.o.rgh[0][300+h0]+S.o.rgh[1][300+h0]+S.o.bh[300+h0];
          float rg0=sigm(S.o.gi[h0]+S.o.bi[h0]+gh00);
          float zg0=sigm(S.o.gi[150+h0]+S.o.bi[150+h0]+gh10);
          float ng0=ftanh(S.o.gi[300+h0]+S.o.bi[300+h0]+rg0*gh20);
          float vn0=fmaf(zg0, S.o.v[h0]-ng0, ng0);
          float gh01=S.o.rgh[0][h1]+S.o.rgh[1][h1]+S.o.bh[h1];
          float gh11=S.o.rgh[0][150+h1]+S.o.rgh[1][150+h1]+S.o.bh[150+h1];
          float gh21=S.o.rgh[0][300+h1]+S.o.rgh[1][300+h1]+S.o.bh[300+h1];
          float rg1=sigm(S.o.gi[h1]+S.o.bi[h1]+gh01);
          float zg1=sigm(S.o.gi[150+h1]+S.o.bi[150+h1]+gh11);
          float ng1=ftanh(S.o.gi[300+h1]+S.o.bi[300+h1]+rg1*gh21);
          float vn1=fmaf(zg1, S.o.v[h1]-ng1, ng1);
          S.o.v[h0]=vn0; S.o.v[h1]=vn1;
          S.o.vp[tid]=pk(vn0,vn1);
          dout[((size_t)(t-1)*32+b)*150+h0]=vn0;
          dout[((size_t)(t-1)*32+b)*150+h1]=vn1;
        }
      }
      __syncthreads();                           // bar2: v/vp (+wup) ready
      // w2 = wup + Wv.v (LDS)
      if(tid<608){
        int h=tid>>2, qd=tid&3;
        float acc=0.f;
        if(h<150){
          #pragma unroll
          for(int p=qd*19;p<qd*19+19;p++) acc=DOT2(S.o.WvU[p*152+h], S.o.vp[p], acc);
        }
        acc+=__shfl_xor(acc,1,64); acc+=__shfl_xor(acc,2,64);
        if(h<150&&qd==0){ h2 ww=uh(S.o.wup[h>>1]); S.o.w2[h]=acc+(float)ww[h&1]; }
      }
      __syncthreads();                           // bar3
      // s[q] = sum_h V[h] tanh(w2[h]+WqUq[q,h]) (LDS)
      {
        int q=tid>>2, hq=tid&3;
        int hp0=hq*19, hp1=(hq==3)?75:hp0+19;
        float acc=0.f;
        for(int hp=hp0;hp<hp1;hp++){
          h2 wp=uh(S.o.WqUq[q*76+hp]);
          acc=fmaf(S.o.V[2*hp],   ftanh(S.o.w2[2*hp]  +(float)wp[0]), acc);
          acc=fmaf(S.o.V[2*hp+1], ftanh(S.o.w2[2*hp+1]+(float)wp[1]), acc);
        }
        acc+=__shfl_xor(acc,1,64); acc+=__shfl_xor(acc,2,64);
        if(hq==0) S.o.s[q]=acc;
      }
      __syncthreads();                           // bar4
      // softmax + pub merged (single wave, shfl pairing)
      if(tid<64){
        float x0=S.o.s[tid],x1=S.o.s[tid+64],x2=S.o.s[tid+128],x3=S.o.s[tid+192];
        float mx=fmaxf(fmaxf(x0,x1),fmaxf(x2,x3));
        #pragma unroll
        for(int o=1;o<64;o<<=1) mx=fmaxf(mx,__shfl_xor(mx,o,64));
        float e0=__expf(x0-mx),e1=__expf(x1-mx),e2=__expf(x2-mx),e3=__expf(x3-mx);
        float sm=e0+e1+e2+e3;
        #pragma unroll
        for(int o=1;o<64;o<<=1) sm+=__shfl_xor(sm,o,64);
        float rs=RCPF(sm);
        float a0=e0*rs, a1=e1*rs, a2v=e2*rs, a3=e3*rs;
        float y0=__shfl_xor(a0,1,64), y1=__shfl_xor(a1,1,64);
        float y2=__shfl_xor(a2v,1,64), y3=__shfl_xor(a3,1,64);
        if(!(tid&1)){
          int w=tid>>1;
          pubw(aP+b*128+w,    (unsigned)(t+1), pk(a0,y0));
          pubw(aP+b*128+32+w, (unsigned)(t+1), pk(a1,y1));
          pubw(aP+b*128+64+w, (unsigned)(t+1), pk(a2v,y2));
          pubw(aP+b*128+96+w, (unsigned)(t+1), pk(a3,y3));
        }
      }
      // gh = Whh.v column-coalesced stream (off critical path, overlaps worker phase)
      {
        int k=tid&511, half=tid>>9;
        if(k<450){
          float ah=0.f;
          int p0=half*38, p1=half?76:38;
          for(int p=p0;p<p1;p++) ah=DOT2(WhhP[p*456+k], S.o.vp[p], ah);
          S.o.rgh[half][k]=ah;
        }
      }
      // rgh/vp next written only after bar1 of next iteration (poll-backed) -> safe
    }
    // epilogue: v_512 -> dout[511]
    if(tid<225){
      int off[4]={gib+tid, gib+226+tid, gib+452+tid, gib+678+tid};
      unsigned gv[4];
      waitN<4>(giP,off,512u,gv,kf);
      float g0=0.f,g1=0.f;
      #pragma unroll
      for(int k=0;k<4;k++){ h2 x=uh(gv[k]); g0+=(float)x[0]; g1+=(float)x[1]; }
      S.o.gi[2*tid]=g0; S.o.gi[2*tid+1]=g1;
    }
    __syncthreads();
    if(tid<150){
      float gh0=S.o.rgh[0][tid]+S.o.rgh[1][tid]+S.o.bh[tid];
      float gh1=S.o.rgh[0][150+tid]+S.o.rgh[1][150+tid]+S.o.bh[150+tid];
      float gh2=S.o.rgh[0][300+tid]+S.o.rgh[1][300+tid]+S.o.bh[300+tid];
      float rg=sigm(S.o.gi[tid]+S.o.bi[tid] + gh0);
      float zg=sigm(S.o.gi[150+tid]+S.o.bi[150+tid] + gh1);
      float ng=ftanh(S.o.gi[300+tid]+S.o.bi[300+tid] + rg*gh2);
      dout[((size_t)511*32+b)*150+tid]=fmaf(zg, S.o.v[tid]-ng, ng);
    }

  } else {
    // ================= WORKER (4 per b): cc, Gc=a.M, gate+c_, gi partial =================
    const int wid = bid-32;
    const int b = wid>>2, s = wid&3;
    for(int o=tid;o<32768;o+=1024){
      int qp=o&127, jl=o>>7;
      int j = s*128 + (jl&127) + ((jl>>7)<<9);
      S.w.M[qp*265+jl] = Mp[((size_t)b*1024+j)*128+qp];
    }
    __syncthreads();
    const size_t uqbase = ((size_t)b*512 + s*128)*128;
    for(int t=0;t<512;++t){
      if(tid<128){
        int wi = (tid<64)? (s*64+tid) : (256+s*64+tid-64);
        unsigned gupr = Gup3u[((size_t)b*512+t)*512 + wi];  // prefetch
        int off[1]={b*128+tid};
        unsigned av[1];
        waitN<1>(aP,off,(unsigned)(t+1),av,kf);
        S.w.a2[tid]=av[0];
        S.w.gup[tid]=gupr;
      }
      __syncthreads();                           // barA: a2/gup ready
      // cc[i] = sum_qp dot2(a2, uq[i])  (uq slice streamed from L2)
      {
        int i=tid>>3, q8=tid&7;
        float acc=0.f;
        const unsigned* up = uqP + uqbase + (size_t)i*128;
        #pragma unroll 4
        for(int kk=0;kk<16;kk++){
          int qp=kk*8+q8;
          acc=DOT2(S.w.a2[qp], up[qp], acc);
        }
        acc+=__shfl_xor(acc,1,64); acc+=__shfl_xor(acc,2,64); acc+=__shfl_xor(acc,4,64);
        if(q8==0) S.w.ccf[i]=acc;
      }
      // Gc[jl] = sum_qp dot2(a2, M[qp][jl])  (stride-265 LDS)
      {
        int jl=tid>>2, qc=tid&3;
        float acc=0.f;
        #pragma unroll 8
        for(int kk=0;kk<32;kk++){
          int qp=kk*4+qc;
          acc=DOT2(S.w.a2[qp], S.w.M[qp*265+jl], acc);
        }
        acc+=__shfl_xor(acc,1,64); acc+=__shfl_xor(acc,2,64);
        if(qc==0) S.w.Gc[jl]=acc;
      }
      __syncthreads();                           // barB: ccf/Gc ready
      // gate + c_ + pack merged (2 j per thread)
      if(tid<128){
        h2 gv=uh(S.w.gup[tid]);
        float c0=sigm(S.w.Gc[2*tid]  +(float)gv[0])*S.w.ccf[(2*tid)&127];
        float c1=sigm(S.w.Gc[2*tid+1]+(float)gv[1])*S.w.ccf[(2*tid+1)&127];
        S.w.cpr[tid]=pk(c0,c1);
      }
      __syncthreads();                           // barC: cpr ready
      // gi partial: column-coalesced WihT stream + LDS-broadcast cpr
      {
        int k=tid&511, half=tid>>9;
        float acc=0.f;
        if(k<450){
          #pragma unroll 8
          for(int m=0;m<64;m++){
            int jpg = half*256 + s*64 + m;
            acc=DOT2(WihTu[(size_t)jpg*456+k], S.w.cpr[half*64+m], acc);
          }
          S.w.rgi[half][k]=acc;
        }
      }
      __syncthreads();                           // barD: rgi ready
      if(tid<225){
        float g0=S.w.rgi[0][2*tid]+S.w.rgi[1][2*tid];
        float g1=S.w.rgi[0][2*tid+1]+S.w.rgi[1][2*tid+1];
        pubw(giP + ((size_t)b*4+s)*226 + tid, (unsigned)(t+1), pk(g0,g1));
      }
    }
  }
}

// ---------------- host ----------------
extern "C" void kernel_launch(void* const* d_in, const int* in_sizes, int n_in,
                              void* d_out, int out_size, void* d_ws, size_t ws_size,
                              hipStream_t stream)
{
  const float* up  = (const float*)d_in[0];
  const float* uq  = (const float*)d_in[1];
  const float* v0  = (const float*)d_in[2];
  const float* Vm  = (const float*)d_in[3];
  const float* Wp  = (const float*)d_in[4];
  const float* Wq  = (const float*)d_in[5];
  const float* Wv  = (const float*)d_in[6];
  const float* Wg  = (const float*)d_in[7];
  const float* W_ih= (const float*)d_in[8];
  const float* W_hh= (const float*)d_in[9];
  const float* b_ih= (const float*)d_in[10];
  const float* b_hh= (const float*)d_in[11];
  float* dout = (float*)d_out;
  char* wsb = (char*)d_ws;

  size_t off = 0;
  auto alloc = [&](size_t bytes)->size_t{ size_t p = off; off = (off + bytes + 255) & ~(size_t)255; return p; };
  size_t oWgupT = alloc((size_t)512*1024*4);      // 2MB; comm aliases after gemms
  size_t oWgcT  = alloc((size_t)512*1024*4);
  size_t oWuph  = alloc((size_t)32*512*152*2);
  size_t oWqUqh = alloc((size_t)32*256*152*2);
  size_t oWihT  = alloc((size_t)512*456*4);
  size_t oWhhP  = alloc((size_t)76*456*4);
  size_t oWvU   = alloc((size_t)76*152*4);
  size_t oUqP   = alloc((size_t)32*512*128*4);
  size_t oMp    = alloc((size_t)32*1024*128*4);
  size_t oGup3  = alloc((size_t)32*512*1024*2);   // WpT/WqT alias (dead before write)
  if(ws_size < off) return;

  float*    WgupT = (float*)(wsb + oWgupT);
  float*    WgcT  = (float*)(wsb + oWgcT);
  _Float16* Wuph  = (_Float16*)(wsb + oWuph);
  _Float16* WqUqh = (_Float16*)(wsb + oWqUqh);
  unsigned* WihT  = (unsigned*)(wsb + oWihT);
  unsigned* WhhP  = (unsigned*)(wsb + oWhhP);
  unsigned* WvU   = (unsigned*)(wsb + oWvU);
  unsigned* uqP   = (unsigned*)(wsb + oUqP);
  unsigned* Mp    = (unsigned*)(wsb + oMp);
  _Float16* Gup3  = (_Float16*)(wsb + oGup3);
  float* WpT = (float*)(wsb + oGup3);
  float* WqT = (float*)(wsb + oGup3 + 307456);

  // tagged pubs alias the (dead-after-gemms) WgupT region
  u64t* comm64 = (u64t*)(wsb + oWgupT);
  u64t* aP  = comm64;              // 32*128 = 4096
  u64t* giP = comm64 + 4096;       // 32*4*226 = 28928 (per-slot contiguous)
  unsigned* kf = (unsigned*)(comm64 + 33024);

  k_fold <<<256,256,0,stream>>>(Wp,Wq,Wg, WpT,WqT,WgupT,WgcT);
  k_fold2<<<256,256,0,stream>>>(W_ih, W_hh, Wv, WihT, WhhP, WvU);
  k_uqp  <<<dim3(32,8),256,0,stream>>>(uq, uqP);
  k_gemm<0><<<dim3(512,1),256,0,stream>>>(up, WpT, Wuph, 150);
  k_gemm<3><<<dim3(256,1),256,0,stream>>>(uq, WqT, WqUqh, 150);
  k_gemm<4><<<dim3(512,4),256,0,stream>>>(up, WgupT, Gup3, 1024);  // WpT/WqT dead now
  k_gemmM<<<dim3(32,8,4),256,0,stream>>>(uq, WgcT, Mp);
  k_init <<<65,1024,0,stream>>>((unsigned*)comm64);                 // WgupT dead now

  int smem = (int)sizeof(SMU);
  hipFuncSetAttribute((const void*)persist, hipFuncAttributeMaxDynamicSharedMemorySize, smem);
  const unsigned* Gup3u  = (const unsigned*)Gup3;
  const unsigned* Wuphu  = (const unsigned*)Wuph;
  const unsigned* WqUqhu = (const unsigned*)WqUqh;
  void* ka[16] = { (void*)&uqP, (void*)&Mp, (void*)&Gup3u, (void*)&Wuphu, (void*)&WqUqhu,
                   (void*)&WihT, (void*)&WhhP, (void*)&WvU,
                   (void*)&v0, (void*)&Vm, (void*)&b_ih, (void*)&b_hh,
                   (void*)&aP, (void*)&giP, (void*)&kf, (void*)&dout };
  hipLaunchCooperativeKernel((const void*)persist, dim3(160), dim3(1024), ka,
                             (unsigned)smem, stream);
}